// Round 5
// baseline (174.619 us; speedup 1.0000x reference)
//
#include <hip/hip_runtime.h>
#include <hip/hip_bf16.h>
#include <math.h>

static constexpr int Dd   = 128;
static constexpr int NH   = 8;
static constexpr int HD   = 16;
static constexpr int NE   = 256;
static constexpr int RR   = 32;
static constexpr int BB   = 4;
static constexpr int TT   = 512;
static constexpr int NTOK = BB * TT;   // 2048
static constexpr int SLOTS = 256;
#define EPSF 1e-6f

__device__ __forceinline__ float elu1(float v) { return v > 0.f ? v + 1.f : expf(v); }
__device__ __forceinline__ float sigm(float v) { return 1.f / (1.f + expf(-v)); }

// ===== k_init: oR=oW@rot, bR=ob@rot, kvW=kdW@kuW, bkv=kdb@kuW+kub; zero accums
__global__ __launch_bounds__(256) void k_init(
    const float* __restrict__ oW, const float* __restrict__ ob,
    const float* __restrict__ rot,
    const float* __restrict__ kdW, const float* __restrict__ kdb,
    const float* __restrict__ kuW, const float* __restrict__ kub,
    float* __restrict__ oR, float* __restrict__ bR,
    float* __restrict__ kvW, float* __restrict__ bkv,
    float* __restrict__ ctx, float* __restrict__ ksum, int* __restrict__ cnt) {
  const int blk = blockIdx.x, tid = threadIdx.x;
  if (blk < 64) {                       // oR: 128x128, K=128
    int row = blk * 2 + (tid >> 7), col = tid & 127;
    const float* ow = oW + row * 128;
    float acc = 0.f;
#pragma unroll 8
    for (int k = 0; k < 128; k++) acc += ow[k] * rot[k * 128 + col];
    oR[row * 128 + col] = acc;
  } else if (blk == 64) {               // bR, bkv, zeroing
    if (tid < 128) {
      float acc = 0.f;
#pragma unroll 8
      for (int k = 0; k < 128; k++) acc += ob[k] * rot[k * 128 + tid];
      bR[tid] = acc;
    }
    {
      float acc = kub[tid];
#pragma unroll
      for (int k = 0; k < 32; k++) acc += kdb[k] * kuW[k * 256 + tid];
      bkv[tid] = acc;
    }
    for (int i = tid; i < 32 * 256; i += 256) ctx[i] = 0.f;
    for (int i = tid; i < 512; i += 256) ksum[i] = 0.f;
    cnt[tid] = 0;
  } else {                              // kvW: 128x256, K=32
    int idx = (blk - 65) * 256 + tid;
    int row = idx >> 8, col = idx & 255;
    const float* kw = kdW + row * 32;
    float acc = 0.f;
#pragma unroll
    for (int k = 0; k < 32; k++) acc += kw[k] * kuW[k * 256 + col];
    kvW[row * 256 + col] = acc;
  }
}

// ===== k_pre: TPB=4, 768 thr: (g1*x)@[qW|kvW], deferred rms scale, elu ======
__global__ __launch_bounds__(768) void k_pre(
    const float* __restrict__ x, const float* __restrict__ g1,
    const float* __restrict__ qW, const float* __restrict__ qb,
    const float* __restrict__ kvW, const float* __restrict__ bkv,
    float* __restrict__ qbuf, float* __restrict__ kvbuf) {
  const int tid = threadIdx.x;
  const int lane = tid & 63;
  const int n0 = blockIdx.x * 4;

  __shared__ float4 xgT[128];
  __shared__ float4 qpart[128];
  __shared__ float4 kvpart[256];
  __shared__ float4 rtmp[2];

  if (tid < 128) {
    int j = tid;
    float g1j = g1[j];
    float v[4], xg[4];
#pragma unroll
    for (int t = 0; t < 4; t++) {
      float xv = x[(n0 + t) * Dd + j];
      v[t] = xv * xv;
      xg[t] = xv * g1j;
    }
    xgT[j] = make_float4(xg[0], xg[1], xg[2], xg[3]);
#pragma unroll
    for (int o = 32; o > 0; o >>= 1) {
#pragma unroll
      for (int t = 0; t < 4; t++) v[t] += __shfl_xor(v[t], o, 64);
    }
    if (lane == 0) rtmp[tid >> 6] = make_float4(v[0], v[1], v[2], v[3]);
  }
  __syncthreads();

  float a0 = 0, a1 = 0, a2 = 0, a3 = 0;
  const bool isq = tid < 256;
  int j, kh;
  if (isq) {
    j = tid & 127; kh = tid >> 7;
    const float* Wp = qW + (kh * 64) * Dd + j;
    const float4* hb = xgT + kh * 64;
#pragma unroll 16
    for (int i = 0; i < 64; i++) {
      float4 h4 = hb[i];
      float w = Wp[i * Dd];
      a0 += h4.x * w; a1 += h4.y * w; a2 += h4.z * w; a3 += h4.w * w;
    }
    if (kh) qpart[j] = make_float4(a0, a1, a2, a3);
  } else {
    int u = tid - 256;
    j = u & 255; kh = u >> 8;
    const float* Wp = kvW + (kh * 64) * 256 + j;
    const float4* hb = xgT + kh * 64;
#pragma unroll 16
    for (int i = 0; i < 64; i++) {
      float4 h4 = hb[i];
      float w = Wp[i * 256];
      a0 += h4.x * w; a1 += h4.y * w; a2 += h4.z * w; a3 += h4.w * w;
    }
    if (kh) kvpart[j] = make_float4(a0, a1, a2, a3);
  }
  __syncthreads();

  if (kh == 0) {
    float r[4];
#pragma unroll
    for (int t = 0; t < 4; t++) {
      float ss = ((const float*)&rtmp[0])[t] + ((const float*)&rtmp[1])[t];
      r[t] = rsqrtf(ss * (1.f / 128.f) + EPSF);
    }
    if (isq) {
      float4 p = qpart[j];
      float bb = qb[j];
      qbuf[(n0 + 0) * Dd + j] = elu1((a0 + p.x) * r[0] + bb);
      qbuf[(n0 + 1) * Dd + j] = elu1((a1 + p.y) * r[1] + bb);
      qbuf[(n0 + 2) * Dd + j] = elu1((a2 + p.z) * r[2] + bb);
      qbuf[(n0 + 3) * Dd + j] = elu1((a3 + p.w) * r[3] + bb);
    } else {
      float4 p = kvpart[j];
      float bb = bkv[j];
      bool isk = (j & 31) < 16;
      float v0 = (a0 + p.x) * r[0] + bb, v1 = (a1 + p.y) * r[1] + bb;
      float v2 = (a2 + p.z) * r[2] + bb, v3 = (a3 + p.w) * r[3] + bb;
      kvbuf[(n0 + 0) * 256 + j] = isk ? elu1(v0) : v0;
      kvbuf[(n0 + 1) * 256 + j] = isk ? elu1(v1) : v1;
      kvbuf[(n0 + 2) * 256 + j] = isk ? elu1(v2) : v2;
      kvbuf[(n0 + 3) * 256 + j] = isk ? elu1(v3) : v3;
    }
  }
}

// ===== k_ctx: 512 blocks = 32 (b,h) x 16 T-chunks of 32 tokens ==============
__global__ __launch_bounds__(256) void k_ctx(const float* __restrict__ kv,
                                             float* __restrict__ ctx,
                                             float* __restrict__ ksum) {
  const int blk = blockIdx.x;
  const int bh = blk >> 4, c = blk & 15;
  const int b = bh >> 3, h = bh & 7;
  const int tid = threadIdx.x;
  const int d = tid >> 4, e = tid & 15;
  __shared__ float sh[32 * 32];
#pragma unroll
  for (int r = 0; r < 4; r++) {
    int lin = r * 256 + tid;
    int tok = lin >> 5, off = lin & 31;
    sh[lin] = kv[((b * TT + c * 32 + tok) * 256) + h * 32 + off];
  }
  __syncthreads();
  float acc = 0.f, ks = 0.f;
#pragma unroll 4
  for (int t = 0; t < 32; t++) {
    float kk = sh[t * 32 + d];
    acc += kk * sh[t * 32 + 16 + e];
    ks += kk;
  }
  atomicAdd(&ctx[bh * 256 + d * 16 + e], acc);
  if (e == 0) atomicAdd(&ksum[bh * 16 + d], ks);
}

// ===== k_mid: TPB=2, 1024 blocks x 512 thr ==================================
__global__ __launch_bounds__(512) void k_mid(
    const float* __restrict__ x, const float* __restrict__ qbuf,
    const float* __restrict__ ctx, const float* __restrict__ ksum,
    const float* __restrict__ oR, const float* __restrict__ bR,
    const float* __restrict__ tqs,
    const float* __restrict__ s1W, const float* __restrict__ s1b,
    const float* __restrict__ s2W, const float* __restrict__ s2b,
    const float* __restrict__ g2, const float* __restrict__ gateW,
    const float* __restrict__ gateb,
    float* __restrict__ xnbuf, float* __restrict__ h2buf,
    float* __restrict__ gw, int* __restrict__ tokslot,
    int* __restrict__ slottok, int* __restrict__ cnt) {
  const int tid = threadIdx.x;
  const int j = tid & 127, g = tid >> 7;
  const int lane = tid & 63;
  const int n0 = blockIdx.x * 2;
  const int b = n0 >> 9;

  __shared__ float2 bufA[128], bufB[128];
  __shared__ float2 part[3][128];
  __shared__ float2 gpart[256];
  __shared__ float2 rtmp[2];
  __shared__ float wvS[4][2]; __shared__ int wiS[4][2];
  __shared__ float zS[4][2];

  float xres[2];
  if (tid < 128) {
#pragma unroll
    for (int t = 0; t < 2; t++) xres[t] = x[(n0 + t) * Dd + j];
  }

  // phase 1: q token-transposed
  if (g < 2) ((float*)&bufA[j])[g] = qbuf[(n0 + g) * Dd + j];
  __syncthreads();

  // phase 2: attention apply (tid<128, K=16)
  if (tid < 128) {
    int h = j >> 4, e = j & 15;
    const float* cpt = ctx + (b * NH + h) * 256;
    const float* kpt = ksum + (b * NH + h) * 16;
    float num[2] = {0, 0}, den[2] = {0, 0};
#pragma unroll
    for (int d = 0; d < 16; d++) {
      float cx = cpt[d * 16 + e], ks = kpt[d];
      float2 q2 = bufA[h * 16 + d];
      num[0] += q2.x * cx; num[1] += q2.y * cx;
      den[0] += q2.x * ks; den[1] += q2.y * ks;
    }
    bufB[j] = make_float2(num[0] / (den[0] + EPSF), num[1] / (den[1] + EPSF));
  }
  __syncthreads();

  // phase 3: z = bufB @ oR + bR; quant -> bufA
  {
    float a0 = 0, a1 = 0;
    const float* Wp = oR + (g * 32) * Dd + j;
#pragma unroll 16
    for (int i = 0; i < 32; i++) {
      float2 h2 = bufB[g * 32 + i];
      float w = Wp[i * Dd];
      a0 += h2.x * w; a1 += h2.y * w;
    }
    if (g) part[g - 1][j] = make_float2(a0, a1);
    __syncthreads();
    float tot[2];
    if (g == 0) {
      float2 p0 = part[0][j], p1 = part[1][j], p2 = part[2][j];
      float bb = bR[j];
      tot[0] = a0 + p0.x + p1.x + p2.x + bb;
      tot[1] = a1 + p0.y + p1.y + p2.y + bb;
      float v[2] = {tot[0] * tot[0], tot[1] * tot[1]};
#pragma unroll
      for (int o = 32; o > 0; o >>= 1) {
        v[0] += __shfl_xor(v[0], o, 64);
        v[1] += __shfl_xor(v[1], o, 64);
      }
      if (lane == 0) rtmp[tid >> 6] = make_float2(v[0], v[1]);
    }
    __syncthreads();
    if (g == 0) {
      float scj = tqs[j];
#pragma unroll
      for (int t = 0; t < 2; t++) {
        float ss = ((const float*)&rtmp[0])[t] + ((const float*)&rtmp[1])[t];
        float mag = sqrtf(ss * (1.f / 128.f) + EPSF);
        float zc = fminf(fmaxf(tot[t], -mag), mag);
        ((float*)&bufA[j])[t] = zc * scj;
      }
    }
    __syncthreads();
  }

  // phase 4: s1/s2 dual GEMV -> xn (+res); bufB = g2*xn; rtmp = sumsq(xn)
  {
    float a0 = 0, a1 = 0;
    const float* Wp = (g < 2 ? s1W : s2W) + ((g & 1) * 64) * Dd + j;
#pragma unroll 16
    for (int i = 0; i < 64; i++) {
      float2 h2 = bufA[(g & 1) * 64 + i];
      float w = Wp[i * Dd];
      a0 += h2.x * w; a1 += h2.y * w;
    }
    if (g) part[g - 1][j] = make_float2(a0, a1);
    __syncthreads();
    if (g == 0) {
      float b1 = s1b[j], b2 = s2b[j];
      float2 p0 = part[0][j], p1 = part[1][j], p2 = part[2][j];
      float gv[2], uv[2], xn[2], v[2];
      gv[0] = a0 + p0.x + b1; gv[1] = a1 + p0.y + b1;
      uv[0] = p1.x + p2.x + b2; uv[1] = p1.y + p2.y + b2;
      float g2j = g2[j];
#pragma unroll
      for (int t = 0; t < 2; t++) {
        xn[t] = xres[t] + gv[t] * sigm(gv[t]) * uv[t];
        xnbuf[(n0 + t) * Dd + j] = xn[t];
        ((float*)&bufB[j])[t] = g2j * xn[t];
        v[t] = xn[t] * xn[t];
      }
#pragma unroll
      for (int o = 32; o > 0; o >>= 1) {
        v[0] += __shfl_xor(v[0], o, 64);
        v[1] += __shfl_xor(v[1], o, 64);
      }
      if (lane == 0) rtmp[tid >> 6] = make_float2(v[0], v[1]);
    }
    __syncthreads();
  }

  // phase 5: gate logits (K-split-2 over 256 cols); r2 at epilogue
  float val[2];
  float r2[2];
  {
    int col = tid & 255, kh = tid >> 8;
    float a0 = 0, a1 = 0;
    const float* Wp = gateW + (kh * 64) * NE + col;
#pragma unroll 16
    for (int i = 0; i < 64; i++) {
      float2 h2 = bufB[kh * 64 + i];
      float w = Wp[i * NE];
      a0 += h2.x * w; a1 += h2.y * w;
    }
    if (kh) gpart[col] = make_float2(a0, a1);
    __syncthreads();
#pragma unroll
    for (int t = 0; t < 2; t++) {
      float ss = ((const float*)&rtmp[0])[t] + ((const float*)&rtmp[1])[t];
      r2[t] = rsqrtf(ss * (1.f / 128.f) + EPSF);
    }
    if (!kh) {
      float2 p = gpart[col];
      float bb = gateb[col];
      val[0] = (a0 + p.x) * r2[0] + bb;
      val[1] = (a1 + p.y) * r2[1] + bb;
    }
    if (tid < 128) {
#pragma unroll
      for (int t = 0; t < 2; t++)
        h2buf[(n0 + t) * Dd + j] = ((const float*)&bufB[j])[t] * r2[t];
    }
  }
  __syncthreads();

  // top-2 over 256 logits (tid<256)
  float m1[2]; int i1[2];
  {
    if (tid < 256) {
      float bv[2]; int bi[2];
#pragma unroll
      for (int t = 0; t < 2; t++) { bv[t] = val[t]; bi[t] = tid; }
#pragma unroll
      for (int o = 32; o > 0; o >>= 1) {
#pragma unroll
        for (int t = 0; t < 2; t++) {
          float wv = __shfl_xor(bv[t], o, 64);
          int wi = __shfl_xor(bi[t], o, 64);
          if (wv > bv[t] || (wv == bv[t] && wi < bi[t])) { bv[t] = wv; bi[t] = wi; }
        }
      }
      if (lane == 0) {
#pragma unroll
        for (int t = 0; t < 2; t++) { wvS[tid >> 6][t] = bv[t]; wiS[tid >> 6][t] = bi[t]; }
      }
    }
    __syncthreads();
    if (tid < 256) {
#pragma unroll
      for (int t = 0; t < 2; t++) {
        m1[t] = wvS[0][t]; i1[t] = wiS[0][t];
#pragma unroll
        for (int w = 1; w < 4; w++) {
          float cv = wvS[w][t]; int ci = wiS[w][t];
          if (cv > m1[t] || (cv == m1[t] && ci < i1[t])) { m1[t] = cv; i1[t] = ci; }
        }
      }
    }
    __syncthreads();
  }
  float m2[2]; int i2[2];
  {
    if (tid < 256) {
      float bv[2]; int bi[2];
#pragma unroll
      for (int t = 0; t < 2; t++) {
        bv[t] = (tid == i1[t]) ? -INFINITY : val[t];
        bi[t] = tid;
      }
#pragma unroll
      for (int o = 32; o > 0; o >>= 1) {
#pragma unroll
        for (int t = 0; t < 2; t++) {
          float wv = __shfl_xor(bv[t], o, 64);
          int wi = __shfl_xor(bi[t], o, 64);
          if (wv > bv[t] || (wv == bv[t] && wi < bi[t])) { bv[t] = wv; bi[t] = wi; }
        }
      }
      if (lane == 0) {
#pragma unroll
        for (int t = 0; t < 2; t++) { wvS[tid >> 6][t] = bv[t]; wiS[tid >> 6][t] = bi[t]; }
      }
    }
    __syncthreads();
    if (tid < 256) {
#pragma unroll
      for (int t = 0; t < 2; t++) {
        m2[t] = wvS[0][t]; i2[t] = wiS[0][t];
#pragma unroll
        for (int w = 1; w < 4; w++) {
          float cv = wvS[w][t]; int ci = wiS[w][t];
          if (cv > m2[t] || (cv == m2[t] && ci < i2[t])) { m2[t] = cv; i2[t] = ci; }
        }
      }
    }
    __syncthreads();
  }
  {
    if (tid < 256) {
      float v[2] = {expf(val[0] - m1[0]), expf(val[1] - m1[1])};
#pragma unroll
      for (int o = 32; o > 0; o >>= 1) {
        v[0] += __shfl_xor(v[0], o, 64);
        v[1] += __shfl_xor(v[1], o, 64);
      }
      if (lane == 0) { zS[tid >> 6][0] = v[0]; zS[tid >> 6][1] = v[1]; }
    }
    __syncthreads();
  }
  if (tid < 2) {
    int t = tid, tok = n0 + t;
    float Z = zS[0][t] + zS[1][t] + zS[2][t] + zS[3][t];
    float p1 = 1.f / Z;
    float p2 = expf(m2[t] - m1[t]) / Z;
    float s = p1 + p2 + EPSF;
    int e1 = i1[t], e2 = i2[t];
    int s1 = atomicAdd(&cnt[e1], 1); if (s1 > SLOTS - 1) s1 = SLOTS - 1;
    int s2 = atomicAdd(&cnt[e2], 1); if (s2 > SLOTS - 1) s2 = SLOTS - 1;
    int sl1 = e1 * SLOTS + s1, sl2 = e2 * SLOTS + s2;
    slottok[sl1] = tok; slottok[sl2] = tok;
    tokslot[tok * 2] = sl1; tokslot[tok * 2 + 1] = sl2;
    gw[tok * 2] = p1 / s; gw[tok * 2 + 1] = p2 / s;
  }
}

// ===== k_exp: 512 blocks = (expert, col-half); 256 thr ======================
__global__ __launch_bounds__(256) void k_exp(const float* __restrict__ h2buf,
                                             const int* __restrict__ slottok,
                                             const int* __restrict__ cnt,
                                             const float* __restrict__ expW,
                                             float* __restrict__ ybuf) {
  const int e = blockIdx.x >> 1, half = blockIdx.x & 1;
  int n = cnt[e]; if (n > SLOTS) n = SLOTS;
  if (n == 0) return;
  const int base = e * SLOTS;
  const int tid = threadIdx.x;
  const int j = (tid & 63) + 64 * half;   // output col
  const int g = tid >> 6;                 // token quarter (4 tokens each)
  __shared__ __align__(16) float hT[128 * 20];
  const float* Wp = expW + (size_t)e * Dd * Dd + j;
  for (int t0 = 0; t0 < n; t0 += 16) {
    int m = n - t0; if (m > 16) m = 16;
    __syncthreads();
    for (int tt = g; tt < m; tt += 4) {
      int tok = slottok[base + t0 + tt];
      int r = tid & 63;
      hT[r * 20 + tt] = h2buf[tok * Dd + r];
      hT[(r + 64) * 20 + tt] = h2buf[tok * Dd + r + 64];
    }
    __syncthreads();
    float acc[4] = {0, 0, 0, 0};
#pragma unroll 8
    for (int i = 0; i < 128; i++) {
      float w = Wp[i * Dd];
      float4 h4 = *(const float4*)&hT[i * 20 + g * 4];   // wave-uniform: broadcast
      acc[0] += h4.x * w; acc[1] += h4.y * w; acc[2] += h4.z * w; acc[3] += h4.w * w;
    }
#pragma unroll
    for (int k = 0; k < 4; k++) {
      int tt = g * 4 + k;
      if (tt < m) ybuf[(size_t)(base + t0 + tt) * Dd + j] = acc[k];
    }
  }
}

// ===== k_post: TPB=2, 1024 blocks x 512 thr =================================
__global__ __launch_bounds__(512) void k_post(
    const float* __restrict__ xnbuf, const float* __restrict__ ybuf,
    const int* __restrict__ tokslot, const float* __restrict__ gw,
    const float* __restrict__ m1W, const float* __restrict__ m1b,
    const float* __restrict__ m2W, const float* __restrict__ m2b,
    float* __restrict__ out) {
  const int tid = threadIdx.x;
  const int j = tid & 127, g = tid >> 7;
  const int lane = tid & 63;
  const int n0 = blockIdx.x * 2;

  __shared__ float2 y1T[128], y2T[128], inT[128], sT[128];
  __shared__ float2 part[3][128];
  __shared__ float2 rtmp[2];
  __shared__ int sSlot[2][2];
  __shared__ float sWt[2][2];

  if (tid < 2) {
    sSlot[tid][0] = tokslot[(n0 + tid) * 2];
    sSlot[tid][1] = tokslot[(n0 + tid) * 2 + 1];
    sWt[tid][0] = gw[(n0 + tid) * 2];
    sWt[tid][1] = gw[(n0 + tid) * 2 + 1];
  }
  __syncthreads();

  if (g < 2) {
    float y1 = ybuf[(size_t)sSlot[g][0] * Dd + j];
    float y2 = ybuf[(size_t)sSlot[g][1] * Dd + j];
    ((float*)&y1T[j])[g] = y1;
    ((float*)&y2T[j])[g] = y2;
    ((float*)&inT[j])[g] = sWt[g][0] * y1 + sWt[g][1] * y2;
  }
  __syncthreads();

  {
    float a0 = 0, a1 = 0;
    const float* Wp = (g < 2 ? m1W : m2W) + ((g & 1) * 64) * Dd + j;
#pragma unroll 16
    for (int i = 0; i < 64; i++) {
      float2 h2 = inT[(g & 1) * 64 + i];
      float w = Wp[i * Dd];
      a0 += h2.x * w; a1 += h2.y * w;
    }
    if (g) part[g - 1][j] = make_float2(a0, a1);
    __syncthreads();
    if (g == 0) {
      float b1 = m1b[j], b2 = m2b[j];
      float2 p0 = part[0][j], p1 = part[1][j], p2 = part[2][j];
      float gv[2], uv[2];
      gv[0] = a0 + p0.x + b1; gv[1] = a1 + p0.y + b1;
      uv[0] = p1.x + p2.x + b2; uv[1] = p1.y + p2.y + b2;
#pragma unroll
      for (int t = 0; t < 2; t++) {
        float sv = gv[t] * sigm(gv[t]) * uv[t];
        ((float*)&sT[j])[t] = sv;
        out[(n0 + t) * Dd + j] = xnbuf[(n0 + t) * Dd + j] + sv;
      }
    }
    __syncthreads();
  }

  if (tid < 128) {
    float v[2];
#pragma unroll
    for (int t = 0; t < 2; t++) {
      float sv = ((const float*)&sT[j])[t];
      float d1 = ((const float*)&y1T[j])[t] - sv;
      float d2 = ((const float*)&y2T[j])[t] - sv;
      v[t] = sWt[t][0] * d1 * d1 + sWt[t][1] * d2 * d2;
    }
#pragma unroll
    for (int o = 32; o > 0; o >>= 1) {
      v[0] += __shfl_xor(v[0], o, 64);
      v[1] += __shfl_xor(v[1], o, 64);
    }
    if (lane == 0) rtmp[tid >> 6] = make_float2(v[0], v[1]);
  }
  __syncthreads();
  if (tid < 2) {
    float s = ((const float*)&rtmp[0])[tid] + ((const float*)&rtmp[1])[tid];
    out[NTOK * Dd + n0 + tid] = expf(-s * (1.f / 128.f));
  }
}

extern "C" void kernel_launch(void* const* d_in, const int* in_sizes, int n_in,
                              void* d_out, int out_size, void* d_ws, size_t ws_size,
                              hipStream_t stream) {
  const float* x   = (const float*)d_in[0];
  const float* g1  = (const float*)d_in[1];
  const float* qW  = (const float*)d_in[2];
  const float* qb  = (const float*)d_in[3];
  const float* kdW = (const float*)d_in[4];
  const float* kdb = (const float*)d_in[5];
  const float* kuW = (const float*)d_in[6];
  const float* kub = (const float*)d_in[7];
  const float* oW  = (const float*)d_in[8];
  const float* ob  = (const float*)d_in[9];
  const float* rot = (const float*)d_in[10];
  const float* tqs = (const float*)d_in[11];
  const float* s1W = (const float*)d_in[12];
  const float* s1b = (const float*)d_in[13];
  const float* s2W = (const float*)d_in[14];
  const float* s2b = (const float*)d_in[15];
  const float* g2  = (const float*)d_in[16];
  const float* gW  = (const float*)d_in[17];
  const float* gb  = (const float*)d_in[18];
  const float* eW  = (const float*)d_in[19];
  const float* m1W = (const float*)d_in[20];
  const float* m1b = (const float*)d_in[21];
  const float* m2W = (const float*)d_in[22];
  const float* m2b = (const float*)d_in[23];
  float* out = (float*)d_out;
  float* ws  = (float*)d_ws;

  float* qbuf   = ws;                     // 262144
  float* kvbuf  = ws + 262144;            // 524288 -> 786432
  float* ctx    = ws + 786432;            // 8192   -> 794624
  float* ksum   = ws + 794624;            // 512    -> 795136
  float* h2buf  = ws + 795136;            // 262144 -> 1057280
  float* xnbuf  = ws + 1057280;           // 262144 -> 1319424
  float* gw     = ws + 1319424;           // 4096   -> 1323520
  float* oRb    = ws + 1323520;           // 16384  -> 1339904
  float* bRb    = ws + 1339904;           // 128    -> 1340032
  float* kvW    = ws + 1340032;           // 32768  -> 1372800
  float* bkv    = ws + 1372800;           // 256    -> 1373056
  int*   cnt     = (int*)(ws + 1373056);  // 256
  int*   tokslot = (int*)(ws + 1373312);  // 4096
  int*   slottok = (int*)(ws + 1377408);  // 65536
  float* ybuf   = ws + 1442944;           // 256*256*128

  k_init<<<193, 256, 0, stream>>>(oW, ob, rot, kdW, kdb, kuW, kub,
                                  oRb, bRb, kvW, bkv, ctx, ksum, cnt);
  k_pre<<<NTOK / 4, 768, 0, stream>>>(x, g1, qW, qb, kvW, bkv, qbuf, kvbuf);
  k_ctx<<<512, 256, 0, stream>>>(kvbuf, ctx, ksum);
  k_mid<<<NTOK / 2, 512, 0, stream>>>(x, qbuf, ctx, ksum, oRb, bRb, tqs,
                                      s1W, s1b, s2W, s2b, g2, gW, gb,
                                      xnbuf, h2buf, gw, tokslot, slottok, cnt);
  k_exp<<<NE * 2, 256, 0, stream>>>(h2buf, slottok, cnt, eW, ybuf);
  k_post<<<NTOK / 2, 512, 0, stream>>>(xnbuf, ybuf, tokslot, gw,
                                       m1W, m1b, m2W, m2b, out);
}